// Round 5
// baseline (438.352 us; speedup 1.0000x reference)
//
#include <hip/hip_runtime.h>
#include <hip/hip_bf16.h>

#define NEMB  4096
#define DIM   128
#define NROWS 32768
#define MARGIN 3.5e-4f   // >= 5x approx-error bound; validated r5-r8
#define RPB   128        // rows per block -> grid 256 = 1 block/CU
#define CHUNK 128        // codes per K-loop iteration
#define NITER 32         // NEMB/CHUNK

typedef _Float16 half8  __attribute__((ext_vector_type(8)));
typedef _Float16 half4v __attribute__((ext_vector_type(4)));
typedef _Float16 half2v __attribute__((ext_vector_type(2)));
typedef float    float16v __attribute__((ext_vector_type(16)));

typedef const __attribute__((address_space(1))) void* gas_ptr;
typedef __attribute__((address_space(3))) void*       las_ptr;

__device__ __forceinline__ void gload16(const void* g, void* l) {
    __builtin_amdgcn_global_load_lds((gas_ptr)g, (las_ptr)l, 16, 0, 0);
}

__device__ __forceinline__ half2v hmin2(half2v a, half2v b) {
    half2v r;
    r.x = (a.x < b.x) ? a.x : b.x;
    r.y = (a.y < b.y) ? a.y : b.y;
    return r;
}

// ---------------- K1: W -> fp16 (scale 2^16) in MFMA-fragment-major layout + ||w||^2 ----
// Wh2 layout: per (slab s = code/32, kchunk c = k/16): 1KB block; half index
// (s*8+c)*512 + (h*32 + (code&31))*8 + (k&7), h=(k>>3)&1.
__launch_bounds__(256)
__global__ void k_prep(const float* __restrict__ W, _Float16* __restrict__ Wh2,
                       float* __restrict__ sww) {
    const int b = blockIdx.x;               // 512 blocks, 8 rows each
    const int t = threadIdx.x;
    const int rbase = b * 8;

    const int i4 = rbase * 32 + t;
    const float4 v = ((const float4*)W)[i4];
    const int r  = i4 >> 5;
    const int k0 = (i4 & 31) * 4;
    const int s  = r >> 5, cs = r & 31, c = k0 >> 4, h2 = (k0 >> 3) & 1, j0 = k0 & 7;
    half4v hv = { (_Float16)(v.x * 65536.0f), (_Float16)(v.y * 65536.0f),
                  (_Float16)(v.z * 65536.0f), (_Float16)(v.w * 65536.0f) };
    *(half4v*)(Wh2 + (s * 8 + c) * 512 + (h2 * 32 + cs) * 8 + j0) = hv;

    if (t < 64) {   // numpy-pairwise ||w||^2 (exact fp32 semantics, validated r3-r8)
        const int row = rbase + (t >> 3);
        const int j   = t & 7;
        const float* p = W + (size_t)row * DIM + j;
        float vv = p[0];
        float rr = __fmul_rn(vv, vv);
        #pragma unroll
        for (int q = 1; q < 16; ++q) { vv = p[q * 8]; rr = __fadd_rn(rr, __fmul_rn(vv, vv)); }
        float o = __shfl_xor(rr, 1, 64); rr = __fadd_rn(rr, o);
        o = __shfl_xor(rr, 2, 64); rr = __fadd_rn(rr, o);
        o = __shfl_xor(rr, 4, 64); rr = __fadd_rn(rr, o);
        if (j == 0) sww[row] = rr;
    }
}

// Peel the first flagged group (lowest word-slot) from the 4 uniform ballot masks.
// j=0/1: word 2l, half 0/1; j=2/3: word 2l+1, half 0/1.  slab s=(wsl-lr)&127,
// group = 2s + half.  Sets G=-1 when no bits remain.
#define PEEL(G) \
    if (m0) { const int l = __builtin_ctzll(m0); m0 &= m0 - 1; \
              G = 2 * ((2 * l - lr) & 127); } \
    else if (m1) { const int l = __builtin_ctzll(m1); m1 &= m1 - 1; \
              G = 2 * ((2 * l - lr) & 127) + 1; } \
    else if (m2) { const int l = __builtin_ctzll(m2); m2 &= m2 - 1; \
              G = 2 * ((2 * l + 1 - lr) & 127); } \
    else if (m3) { const int l = __builtin_ctzll(m3); m3 &= m3 - 1; \
              G = 2 * ((2 * l + 1 - lr) & 127) + 1; } \
    else G = -1;

// ---------------- K2: R1 structure + lane-per-code refine (R13) ----------------
// Scan: UNCHANGED from the 145us R1 kernel (LDS-dbuf DMA, barrier-pipelined).
// Refine: per row, peel up to 4 flagged groups per pass; lane quadrant qq picks
// the group, lane&15 the code -> 64 exact distances in parallel, one gather wait,
// 4-way-ILP fmaf chains, one 6-stage argmin.  Arithmetic bitwise-identical to the
// validated quarter-split (+pairwise) ordering.
__global__ __launch_bounds__(1024, 4)
void k_main(const float* __restrict__ x, const _Float16* __restrict__ Wh2,
            const float* __restrict__ W, const float* __restrict__ sww,
            float* __restrict__ out0, float* __restrict__ out1,
            float* __restrict__ out_idx, float* __restrict__ part) {
    __shared__ _Float16 sA[2 * CHUNK * DIM];   // 64 KB double buffer
    __shared__ _Float16 gbuf[RPB * 256];       // 64 KB group minima (swizzled)
    __shared__ float ssw[NEMB];                // 16 KB sww copy

    const int tid  = threadIdx.x;
    const int wv   = tid >> 6;      // 0..15
    const int lane = tid & 63;
    const int l31  = lane & 31;
    const int h    = lane >> 5;
    const int r0   = blockIdx.x * RPB;
    const int mt   = wv & 3;        // 32-code slab within chunk
    const int np   = wv >> 2;       // ntile 0..3 (rows np*32..np*32+31)

    ((float4*)ssw)[tid] = ((const float4*)sww)[tid];

    // B fragments: x rows of ntile np -> fp16 regs, B[n=lane&31][k=h*8+j] per 16-k chunk
    half8 bfr[8];
    {
        const float* xr = x + (size_t)(r0 + np * 32 + l31) * DIM + h * 8;
        #pragma unroll
        for (int c = 0; c < 8; ++c) {
            const float4 u0 = *(const float4*)(xr + c * 16);
            const float4 u1 = *(const float4*)(xr + c * 16 + 4);
            bfr[c] = (half8){ (_Float16)u0.x, (_Float16)u0.y, (_Float16)u0.z, (_Float16)u0.w,
                              (_Float16)u1.x, (_Float16)u1.y, (_Float16)u1.z, (_Float16)u1.w };
        }
    }

    // sxx (numpy-pairwise exact) for this wave's 8 refine rows, kept in regs
    float sxx_reg;
    {
        const float* ps = x + (size_t)(r0 + wv * 8 + (lane >> 3)) * DIM + (lane & 7);
        float vv = ps[0];
        float rr = __fmul_rn(vv, vv);
        #pragma unroll
        for (int q = 1; q < 16; ++q) { vv = ps[q * 8]; rr = __fadd_rn(rr, __fmul_rn(vv, vv)); }
        float o = __shfl_xor(rr, 1, 64); rr = __fadd_rn(rr, o);
        o = __shfl_xor(rr, 2, 64); rr = __fadd_rn(rr, o);
        o = __shfl_xor(rr, 4, 64); rr = __fadd_rn(rr, o);
        sxx_reg = rr;
    }

    // prologue DMA: chunk `start` -> buffer 0
    const int start = (blockIdx.x >> 3) & 31;
    {
        const char* src = (const char*)Wh2 + (size_t)start * (CHUNK * DIM * 2);
        #pragma unroll
        for (int r = 0; r < 2; ++r)
            gload16(src + wv * 2048 + r * 1024 + lane * 16, (char*)sA + wv * 2048 + r * 1024);
    }

    for (int it = 0; it < NITER; ++it) {
        __syncthreads();   // drains DMA issued one full iteration ago
        if (it + 1 < NITER) {
            const int nc = (start + it + 1) & (NITER - 1);
            const char* src = (const char*)Wh2 + (size_t)nc * (CHUNK * DIM * 2);
            char* dst = (char*)sA + ((it + 1) & 1) * (CHUNK * DIM * 2);
            #pragma unroll
            for (int r = 0; r < 2; ++r)
                gload16(src + wv * 2048 + r * 1024 + lane * 16, dst + wv * 2048 + r * 1024);
        }
        const int cb = (start + it) & (NITER - 1);

        const _Float16* curb = sA + (it & 1) * (CHUNK * DIM);
        float16v acc;
        #pragma unroll
        for (int i = 0; i < 16; ++i) acc[i] = 0.f;

        #pragma unroll
        for (int c = 0; c < 8; ++c) {
            const half8 a = *(const half8*)(curb + (mt * 8 + c) * 512 + lane * 8);
            acc = __builtin_amdgcn_mfma_f32_32x32x16_f16(a, bfr[c], acc, 0, 0, 0);
        }

        // epilogue: s~ = sww - acc*2^-15; two 16-code groups per slab; 1 shfl total
        const int s = cb * 4 + mt;   // global 32-code slab [0,128)
        const float4 swq0 = *(const float4*)((const char*)ssw + s * 128 + h * 16);
        const float4 swq1 = *(const float4*)((const char*)ssw + s * 128 + h * 16 + 32);
        const float4 swq2 = *(const float4*)((const char*)ssw + s * 128 + h * 16 + 64);
        const float4 swq3 = *(const float4*)((const char*)ssw + s * 128 + h * 16 + 96);
        float g0 = fmaf(acc[0], -0x1p-15f, swq0.x);
        g0 = fminf(g0, fmaf(acc[1], -0x1p-15f, swq0.y));
        g0 = fminf(g0, fmaf(acc[2], -0x1p-15f, swq0.z));
        g0 = fminf(g0, fmaf(acc[3], -0x1p-15f, swq0.w));
        g0 = fminf(g0, fmaf(acc[4], -0x1p-15f, swq1.x));
        g0 = fminf(g0, fmaf(acc[5], -0x1p-15f, swq1.y));
        g0 = fminf(g0, fmaf(acc[6], -0x1p-15f, swq1.z));
        g0 = fminf(g0, fmaf(acc[7], -0x1p-15f, swq1.w));
        float g1 = fmaf(acc[8], -0x1p-15f, swq2.x);
        g1 = fminf(g1, fmaf(acc[9],  -0x1p-15f, swq2.y));
        g1 = fminf(g1, fmaf(acc[10], -0x1p-15f, swq2.z));
        g1 = fminf(g1, fmaf(acc[11], -0x1p-15f, swq2.w));
        g1 = fminf(g1, fmaf(acc[12], -0x1p-15f, swq3.x));
        g1 = fminf(g1, fmaf(acc[13], -0x1p-15f, swq3.y));
        g1 = fminf(g1, fmaf(acc[14], -0x1p-15f, swq3.z));
        g1 = fminf(g1, fmaf(acc[15], -0x1p-15f, swq3.w));
        union { half2v h2; int u; } cu, ot;
        cu.h2.x = (_Float16)g0; cu.h2.y = (_Float16)g1;   // groups 2s, 2s+1
        ot.u = __shfl_xor(cu.u, 32, 64);
        cu.h2 = hmin2(cu.h2, ot.h2);
        if (h == 0) {
            const int row = np * 32 + l31;                // local row
            const int ws  = (s + row) & 127;              // swizzled word slot
            ((int*)gbuf)[row * 128 + ws] = cu.u;
        }
    }

    __syncthreads();

    // ---- fused flag + exact refine: lane-per-code batches (R13) ----
    const int lc = lane & 15;       // code within group
    const int qq = lane >> 4;       // group quadrant
    float p_acc = 0.f;
    for (int t = 0; t < 8; ++t) {
        const int lr  = wv * 8 + t;
        const int row = r0 + lr;

        const int2 gw = *(const int2*)((const char*)gbuf + lr * 512 + lane * 8);
        union { half2v h2; int u; } pa, pb;
        pa.u = gw.x; pb.u = gw.y;
        const float v0 = (float)pa.h2.x, v1 = (float)pa.h2.y;
        const float v2 = (float)pb.h2.x, v3 = (float)pb.h2.y;
        float m = fminf(fminf(v0, v1), fminf(v2, v3));
        #pragma unroll
        for (int off = 1; off < 64; off <<= 1) m = fminf(m, __shfl_xor(m, off, 64));
        const float thr = m + MARGIN;
        unsigned long long m0 = __ballot(v0 <= thr);
        unsigned long long m1 = __ballot(v1 <= thr);
        unsigned long long m2 = __ballot(v2 <= thr);
        unsigned long long m3 = __ballot(v3 <= thr);

        const float sxr = __shfl(sxx_reg, t * 8, 64);
        const float* xr = x + (size_t)row * DIM;
        float bv = 3.0e38f;
        int   bi = 0x7fffffff;

        while (m0 | m1 | m2 | m3) {     // usually exactly one pass
            int gid0, gid1, gid2, gid3;
            PEEL(gid0); PEEL(gid1); PEEL(gid2); PEEL(gid3);
            const int g = (qq == 0) ? gid0 : (qq == 1) ? gid1 : (qq == 2) ? gid2 : gid3;
            const bool val = (g >= 0);
            const int c = (val ? g : 0) * 16 + lc;
            const float* wr = W + (size_t)c * DIM;
            // exact distance, validated ordering: 4 serial-fmaf quarters, pairwise sum
            float q0 = 0.f, q1 = 0.f, q2 = 0.f, q3 = 0.f;
            #pragma unroll
            for (int k = 0; k < 32; ++k) q0 = fmaf(xr[k],      wr[k],      q0);
            #pragma unroll
            for (int k = 0; k < 32; ++k) q1 = fmaf(xr[32 + k], wr[32 + k], q1);
            #pragma unroll
            for (int k = 0; k < 32; ++k) q2 = fmaf(xr[64 + k], wr[64 + k], q2);
            #pragma unroll
            for (int k = 0; k < 32; ++k) q3 = fmaf(xr[96 + k], wr[96 + k], q3);
            const float dot = __fadd_rn(__fadd_rn(q0, q1), __fadd_rn(q2, q3));
            const float A = __fadd_rn(sxr, ssw[c]);
            float d = __fsub_rn(A, __fmul_rn(2.0f, dot));
            int  cc = c;
            if (!val) { d = 3.0e38f; cc = 0x7fffffff; }
            if (d < bv || (d == bv && cc < bi)) { bv = d; bi = cc; }
        }

        // 6-stage argmin with smallest-index tiebreak (associative -> order-safe)
        #pragma unroll
        for (int off = 1; off < 64; off <<= 1) {
            const float ov = __shfl_xor(bv, off, 64);
            const int   oi = __shfl_xor(bi, off, 64);
            if (ov < bv || (ov == bv && oi < bi)) { bv = ov; bi = oi; }
        }

        const float2 wv2 = *(const float2*)(W + (size_t)bi * DIM + lane * 2);
        const float2 xv2 = *(const float2*)(xr + lane * 2);
        const float d0 = wv2.x - xv2.x, d1 = wv2.y - xv2.y;
        const float p = fmaf(d0, d0, d1 * d1);
        *(float2*)(out0 + (size_t)row * DIM + lane * 2) = wv2;
        *(float2*)(out1 + (size_t)row * DIM + lane * 2) = wv2;
        p_acc = __fadd_rn(p_acc, p);
        if (lane == 0) out_idx[row] = (float)bi;
    }
    // one loss partial per wave -> 4096 total
    #pragma unroll
    for (int off = 32; off > 0; off >>= 1) p_acc += __shfl_down(p_acc, off, 64);
    if (lane == 0) part[blockIdx.x * 16 + wv] = p_acc;
}

// ---------------- K3: reduce 4096 per-wave partials -> loss ----------------
__global__ void k_lsum(const float* __restrict__ part, float* __restrict__ out_loss) {
    __shared__ float red[1024];
    const int tid = threadIdx.x;
    const float4 v = ((const float4*)part)[tid];
    red[tid] = (v.x + v.y) + (v.z + v.w);
    __syncthreads();
    #pragma unroll
    for (int w = 512; w > 0; w >>= 1) {
        if (tid < w) red[tid] += red[tid + w];
        __syncthreads();
    }
    if (tid == 0) out_loss[0] = red[0] * 1.25f / (float)(NROWS * DIM);
}

extern "C" void kernel_launch(void* const* d_in, const int* in_sizes, int n_in,
                              void* d_out, int out_size, void* d_ws, size_t ws_size,
                              hipStream_t stream) {
    const float* x = (const float*)d_in[0];   // [32768,128]
    const float* W = (const float*)d_in[1];   // [4096,128]
    float* out = (float*)d_out;

    float* out_q2d  = out;
    float* out_qst  = out + (size_t)NROWS * DIM;
    float* out_loss = out + (size_t)2 * NROWS * DIM;
    float* out_idx  = out + (size_t)2 * NROWS * DIM + 1;

    // ws layout: sww | part | Wh2  (~1.2 MB)
    float* ws   = (float*)d_ws;
    float* sww  = ws;                                   // 4096
    float* part = ws + 4096;                            // 4096 used (region 32768)
    _Float16* Wh2 = (_Float16*)(ws + 4096 + 32768);     // 4096*128 fp16, fragment-major

    k_prep<<<NEMB / 8, 256, 0, stream>>>(W, Wh2, sww);
    k_main<<<NROWS / RPB, 1024, 0, stream>>>(x, Wh2, W, sww,
                                             out_q2d, out_qst, out_idx, part);
    k_lsum<<<1, 1024, 0, stream>>>(part, out_loss);
}

// Round 6
// 198.834 us; speedup vs baseline: 2.2046x; 2.2046x over previous
//
#include <hip/hip_runtime.h>
#include <hip/hip_bf16.h>

#define NEMB  4096
#define DIM   128
#define NROWS 32768
#define MARGIN 3.5e-4f   // >= 5x approx-error bound; validated r5-r8
#define RPB   128        // rows per block -> grid 256 = 1 block/CU
#define CHUNK 128        // codes per K-loop iteration
#define NITER 32         // NEMB/CHUNK

typedef _Float16 half8  __attribute__((ext_vector_type(8)));
typedef _Float16 half4v __attribute__((ext_vector_type(4)));
typedef _Float16 half2v __attribute__((ext_vector_type(2)));
typedef float    float16v __attribute__((ext_vector_type(16)));

typedef const __attribute__((address_space(1))) void* gas_ptr;
typedef __attribute__((address_space(3))) void*       las_ptr;

__device__ __forceinline__ void gload16(const void* g, void* l) {
    __builtin_amdgcn_global_load_lds((gas_ptr)g, (las_ptr)l, 16, 0, 0);
}

__device__ __forceinline__ half2v hmin2(half2v a, half2v b) {
    half2v r;
    r.x = (a.x < b.x) ? a.x : b.x;
    r.y = (a.y < b.y) ? a.y : b.y;
    return r;
}

// ---------------- K1: W -> fp16 (scale 2^16) in MFMA-fragment-major layout + ||w||^2 ----
// Wh2 layout: per (slab s = code/32, kchunk c = k/16): 1KB block; half index
// (s*8+c)*512 + (h*32 + (code&31))*8 + (k&7), h=(k>>3)&1.
__launch_bounds__(256)
__global__ void k_prep(const float* __restrict__ W, _Float16* __restrict__ Wh2,
                       float* __restrict__ sww) {
    const int b = blockIdx.x;               // 512 blocks, 8 rows each
    const int t = threadIdx.x;
    const int rbase = b * 8;

    const int i4 = rbase * 32 + t;
    const float4 v = ((const float4*)W)[i4];
    const int r  = i4 >> 5;
    const int k0 = (i4 & 31) * 4;
    const int s  = r >> 5, cs = r & 31, c = k0 >> 4, h2 = (k0 >> 3) & 1, j0 = k0 & 7;
    half4v hv = { (_Float16)(v.x * 65536.0f), (_Float16)(v.y * 65536.0f),
                  (_Float16)(v.z * 65536.0f), (_Float16)(v.w * 65536.0f) };
    *(half4v*)(Wh2 + (s * 8 + c) * 512 + (h2 * 32 + cs) * 8 + j0) = hv;

    if (t < 64) {   // numpy-pairwise ||w||^2 (exact fp32 semantics, validated r3-r8)
        const int row = rbase + (t >> 3);
        const int j   = t & 7;
        const float* p = W + (size_t)row * DIM + j;
        float vv = p[0];
        float rr = __fmul_rn(vv, vv);
        #pragma unroll
        for (int q = 1; q < 16; ++q) { vv = p[q * 8]; rr = __fadd_rn(rr, __fmul_rn(vv, vv)); }
        float o = __shfl_xor(rr, 1, 64); rr = __fadd_rn(rr, o);
        o = __shfl_xor(rr, 2, 64); rr = __fadd_rn(rr, o);
        o = __shfl_xor(rr, 4, 64); rr = __fadd_rn(rr, o);
        if (j == 0) sww[row] = rr;
    }
}

// ---------------- K2: R1 structure + float4 candidate eval (R14) ----------------
// Scan: UNCHANGED from the 145us R1 kernel (LDS-dbuf DMA, barrier-pipelined).
// Refine: same lane->(code,quarter) ownership and bit-identical fmaf order, but
// x quarter hoisted out of the item loop and W quarter loaded as 8 float4s
// (was 32 scalar dwords) -> 4x fewer L1 line-transactions per candidate.
__global__ __launch_bounds__(1024, 4)
void k_main(const float* __restrict__ x, const _Float16* __restrict__ Wh2,
            const float* __restrict__ W, const float* __restrict__ sww,
            float* __restrict__ out0, float* __restrict__ out1,
            float* __restrict__ out_idx, float* __restrict__ part) {
    __shared__ _Float16 sA[2 * CHUNK * DIM];   // 64 KB double buffer
    __shared__ _Float16 gbuf[RPB * 256];       // 64 KB group minima (swizzled)
    __shared__ float ssw[NEMB];                // 16 KB sww copy

    const int tid  = threadIdx.x;
    const int wv   = tid >> 6;      // 0..15
    const int lane = tid & 63;
    const int l31  = lane & 31;
    const int h    = lane >> 5;
    const int r0   = blockIdx.x * RPB;
    const int mt   = wv & 3;        // 32-code slab within chunk
    const int np   = wv >> 2;       // ntile 0..3 (rows np*32..np*32+31)

    ((float4*)ssw)[tid] = ((const float4*)sww)[tid];

    // B fragments: x rows of ntile np -> fp16 regs, B[n=lane&31][k=h*8+j] per 16-k chunk
    half8 bfr[8];
    {
        const float* xr = x + (size_t)(r0 + np * 32 + l31) * DIM + h * 8;
        #pragma unroll
        for (int c = 0; c < 8; ++c) {
            const float4 u0 = *(const float4*)(xr + c * 16);
            const float4 u1 = *(const float4*)(xr + c * 16 + 4);
            bfr[c] = (half8){ (_Float16)u0.x, (_Float16)u0.y, (_Float16)u0.z, (_Float16)u0.w,
                              (_Float16)u1.x, (_Float16)u1.y, (_Float16)u1.z, (_Float16)u1.w };
        }
    }

    // sxx (numpy-pairwise exact) for this wave's 8 refine rows, kept in regs
    float sxx_reg;
    {
        const float* ps = x + (size_t)(r0 + wv * 8 + (lane >> 3)) * DIM + (lane & 7);
        float vv = ps[0];
        float rr = __fmul_rn(vv, vv);
        #pragma unroll
        for (int q = 1; q < 16; ++q) { vv = ps[q * 8]; rr = __fadd_rn(rr, __fmul_rn(vv, vv)); }
        float o = __shfl_xor(rr, 1, 64); rr = __fadd_rn(rr, o);
        o = __shfl_xor(rr, 2, 64); rr = __fadd_rn(rr, o);
        o = __shfl_xor(rr, 4, 64); rr = __fadd_rn(rr, o);
        sxx_reg = rr;
    }

    // prologue DMA: chunk `start` -> buffer 0
    const int start = (blockIdx.x >> 3) & 31;
    {
        const char* src = (const char*)Wh2 + (size_t)start * (CHUNK * DIM * 2);
        #pragma unroll
        for (int r = 0; r < 2; ++r)
            gload16(src + wv * 2048 + r * 1024 + lane * 16, (char*)sA + wv * 2048 + r * 1024);
    }

    for (int it = 0; it < NITER; ++it) {
        __syncthreads();   // drains DMA issued one full iteration ago
        if (it + 1 < NITER) {
            const int nc = (start + it + 1) & (NITER - 1);
            const char* src = (const char*)Wh2 + (size_t)nc * (CHUNK * DIM * 2);
            char* dst = (char*)sA + ((it + 1) & 1) * (CHUNK * DIM * 2);
            #pragma unroll
            for (int r = 0; r < 2; ++r)
                gload16(src + wv * 2048 + r * 1024 + lane * 16, dst + wv * 2048 + r * 1024);
        }
        const int cb = (start + it) & (NITER - 1);

        const _Float16* curb = sA + (it & 1) * (CHUNK * DIM);
        float16v acc;
        #pragma unroll
        for (int i = 0; i < 16; ++i) acc[i] = 0.f;

        #pragma unroll
        for (int c = 0; c < 8; ++c) {
            const half8 a = *(const half8*)(curb + (mt * 8 + c) * 512 + lane * 8);
            acc = __builtin_amdgcn_mfma_f32_32x32x16_f16(a, bfr[c], acc, 0, 0, 0);
        }

        // epilogue: s~ = sww - acc*2^-15; two 16-code groups per slab; 1 shfl total
        const int s = cb * 4 + mt;   // global 32-code slab [0,128)
        const float4 swq0 = *(const float4*)((const char*)ssw + s * 128 + h * 16);
        const float4 swq1 = *(const float4*)((const char*)ssw + s * 128 + h * 16 + 32);
        const float4 swq2 = *(const float4*)((const char*)ssw + s * 128 + h * 16 + 64);
        const float4 swq3 = *(const float4*)((const char*)ssw + s * 128 + h * 16 + 96);
        float g0 = fmaf(acc[0], -0x1p-15f, swq0.x);
        g0 = fminf(g0, fmaf(acc[1], -0x1p-15f, swq0.y));
        g0 = fminf(g0, fmaf(acc[2], -0x1p-15f, swq0.z));
        g0 = fminf(g0, fmaf(acc[3], -0x1p-15f, swq0.w));
        g0 = fminf(g0, fmaf(acc[4], -0x1p-15f, swq1.x));
        g0 = fminf(g0, fmaf(acc[5], -0x1p-15f, swq1.y));
        g0 = fminf(g0, fmaf(acc[6], -0x1p-15f, swq1.z));
        g0 = fminf(g0, fmaf(acc[7], -0x1p-15f, swq1.w));
        float g1 = fmaf(acc[8], -0x1p-15f, swq2.x);
        g1 = fminf(g1, fmaf(acc[9],  -0x1p-15f, swq2.y));
        g1 = fminf(g1, fmaf(acc[10], -0x1p-15f, swq2.z));
        g1 = fminf(g1, fmaf(acc[11], -0x1p-15f, swq2.w));
        g1 = fminf(g1, fmaf(acc[12], -0x1p-15f, swq3.x));
        g1 = fminf(g1, fmaf(acc[13], -0x1p-15f, swq3.y));
        g1 = fminf(g1, fmaf(acc[14], -0x1p-15f, swq3.z));
        g1 = fminf(g1, fmaf(acc[15], -0x1p-15f, swq3.w));
        union { half2v h2; int u; } cu, ot;
        cu.h2.x = (_Float16)g0; cu.h2.y = (_Float16)g1;   // groups 2s, 2s+1
        ot.u = __shfl_xor(cu.u, 32, 64);
        cu.h2 = hmin2(cu.h2, ot.h2);
        if (h == 0) {
            const int row = np * 32 + l31;                // local row
            const int ws  = (s + row) & 127;              // swizzled word slot
            ((int*)gbuf)[row * 128 + ws] = cu.u;
        }
    }

    __syncthreads();

    // ---- fused flag + exact refine (numpy fp32 semantics) + outputs ----
    const int cig = lane >> 2;
    const int kp  = lane & 3;
    float p_acc = 0.f;
    for (int t = 0; t < 8; ++t) {
        const int lr  = wv * 8 + t;
        const int row = r0 + lr;

        const int2 gw = *(const int2*)((const char*)gbuf + lr * 512 + lane * 8);
        union { half2v h2; int u; } pa, pb;
        pa.u = gw.x; pb.u = gw.y;
        const float v0 = (float)pa.h2.x, v1 = (float)pa.h2.y;
        const float v2 = (float)pb.h2.x, v3 = (float)pb.h2.y;
        float m = fminf(fminf(v0, v1), fminf(v2, v3));
        #pragma unroll
        for (int off = 1; off < 64; off <<= 1) m = fminf(m, __shfl_xor(m, off, 64));
        const float thr = m + MARGIN;
        unsigned long long bal[4];
        bal[0] = __ballot(v0 <= thr);
        bal[1] = __ballot(v1 <= thr);
        bal[2] = __ballot(v2 <= thr);
        bal[3] = __ballot(v3 <= thr);

        const float sxr = __shfl(sxx_reg, t * 8, 64);
        const float* xr = x + (size_t)row * DIM;

        // hoisted x quarter (was re-loaded scalar per candidate item)
        float4 xv[8];
        {
            const float4* xq4 = (const float4*)(xr + kp * 32);
            #pragma unroll
            for (int j2 = 0; j2 < 8; ++j2) xv[j2] = xq4[j2];
        }

        float bv = 3.0e38f;
        int   bi = 0x7fffffff;

        #pragma unroll
        for (int j = 0; j < 4; ++j) {
            unsigned long long msk = bal[j];
            while (msk) {
                const int l = __builtin_ctzll(msk);
                msk &= msk - 1;
                const int wsl = 2 * l + (j >> 1);
                const int g   = 2 * ((wsl - lr) & 127) + (j & 1);
                const int c   = g * 16 + cig;
                // W quarter as 8 float4 (bit-identical fmaf order vs scalar k-loop)
                const float4* wq4 = (const float4*)(W + (size_t)c * DIM + kp * 32);
                float dot = 0.f;
                #pragma unroll
                for (int j2 = 0; j2 < 8; ++j2) {
                    const float4 wv4 = wq4[j2];
                    dot = fmaf(xv[j2].x, wv4.x, dot);
                    dot = fmaf(xv[j2].y, wv4.y, dot);
                    dot = fmaf(xv[j2].z, wv4.z, dot);
                    dot = fmaf(xv[j2].w, wv4.w, dot);
                }
                float o = __shfl_xor(dot, 1, 64); dot = __fadd_rn(dot, o);
                o = __shfl_xor(dot, 2, 64); dot = __fadd_rn(dot, o);
                const float A = __fadd_rn(sxr, ssw[c]);
                const float d = __fsub_rn(A, __fmul_rn(2.0f, dot));
                if (d < bv || (d == bv && c < bi)) { bv = d; bi = c; }
            }
        }
        #pragma unroll
        for (int off = 1; off < 64; off <<= 1) {
            const float ov = __shfl_xor(bv, off, 64);
            const int   oi = __shfl_xor(bi, off, 64);
            if (ov < bv || (ov == bv && oi < bi)) { bv = ov; bi = oi; }
        }

        const float2 wv2 = *(const float2*)(W + (size_t)bi * DIM + lane * 2);
        const float2 xv2 = *(const float2*)(xr + lane * 2);
        const float d0 = wv2.x - xv2.x, d1 = wv2.y - xv2.y;
        const float p = fmaf(d0, d0, d1 * d1);
        *(float2*)(out0 + (size_t)row * DIM + lane * 2) = wv2;
        *(float2*)(out1 + (size_t)row * DIM + lane * 2) = wv2;
        p_acc = __fadd_rn(p_acc, p);
        if (lane == 0) out_idx[row] = (float)bi;
    }
    // one loss partial per wave -> 4096 total
    #pragma unroll
    for (int off = 32; off > 0; off >>= 1) p_acc += __shfl_down(p_acc, off, 64);
    if (lane == 0) part[blockIdx.x * 16 + wv] = p_acc;
}

// ---------------- K3: reduce 4096 per-wave partials -> loss ----------------
__global__ void k_lsum(const float* __restrict__ part, float* __restrict__ out_loss) {
    __shared__ float red[1024];
    const int tid = threadIdx.x;
    const float4 v = ((const float4*)part)[tid];
    red[tid] = (v.x + v.y) + (v.z + v.w);
    __syncthreads();
    #pragma unroll
    for (int w = 512; w > 0; w >>= 1) {
        if (tid < w) red[tid] += red[tid + w];
        __syncthreads();
    }
    if (tid == 0) out_loss[0] = red[0] * 1.25f / (float)(NROWS * DIM);
}

extern "C" void kernel_launch(void* const* d_in, const int* in_sizes, int n_in,
                              void* d_out, int out_size, void* d_ws, size_t ws_size,
                              hipStream_t stream) {
    const float* x = (const float*)d_in[0];   // [32768,128]
    const float* W = (const float*)d_in[1];   // [4096,128]
    float* out = (float*)d_out;

    float* out_q2d  = out;
    float* out_qst  = out + (size_t)NROWS * DIM;
    float* out_loss = out + (size_t)2 * NROWS * DIM;
    float* out_idx  = out + (size_t)2 * NROWS * DIM + 1;

    // ws layout: sww | part | Wh2  (~1.2 MB)
    float* ws   = (float*)d_ws;
    float* sww  = ws;                                   // 4096
    float* part = ws + 4096;                            // 4096 used (region 32768)
    _Float16* Wh2 = (_Float16*)(ws + 4096 + 32768);     // 4096*128 fp16, fragment-major

    k_prep<<<NEMB / 8, 256, 0, stream>>>(W, Wh2, sww);
    k_main<<<NROWS / RPB, 1024, 0, stream>>>(x, Wh2, W, sww,
                                             out_q2d, out_qst, out_idx, part);
    k_lsum<<<1, 1024, 0, stream>>>(part, out_loss);
}